// Round 1
// baseline (1259.885 us; speedup 1.0000x reference)
//
#include <hip/hip_runtime.h>
#include <math.h>

// Problem constants (fixed by reference)
#define BB 32     // batch
#define CC 512    // channels
#define CQ 64     // qk channels
#define NN 1024   // Nq = Nk = 32*32
#define NT 64     // n/m tile

// ---------------------------------------------------------------------------
// Wv [o][c] -> WvT [c][o]  (1 MB, trivial)
// ---------------------------------------------------------------------------
__global__ __launch_bounds__(256) void k_transpose(const float* __restrict__ Wv,
                                                   float* __restrict__ WvT) {
    __shared__ float tile[32][33];
    int bx = blockIdx.x, by = blockIdx.y;
    int tx = threadIdx.x & 31, ty = threadIdx.x >> 5;  // 32 x 8
#pragma unroll
    for (int k = 0; k < 4; ++k) {
        int row = ty + k * 8;
        tile[row][tx] = Wv[(size_t)(by * 32 + row) * CC + bx * 32 + tx];
    }
    __syncthreads();
#pragma unroll
    for (int k = 0; k < 4; ++k) {
        int row = ty + k * 8;
        WvT[(size_t)(bx * 32 + row) * CC + by * 32 + tx] = tile[tx][row];
    }
}

// ---------------------------------------------------------------------------
// Q[b][cq][n] = sum_c Wq[cq][c] * face[b][c][n] + bq[cq]   (sel=0)
// K[b][cq][m] = sum_c Wk[cq][c] * audio[b][c][m] + bk[cq]  (sel=1)
// grid (16 ntiles, 2, B), block 256. Wave w owns cq in [16w,16w+16).
// W rows are wave-uniform -> scalar loads; face/audio chunk staged in LDS.
// ---------------------------------------------------------------------------
__global__ __launch_bounds__(256) void k_proj(const float* __restrict__ face,
                                              const float* __restrict__ audio,
                                              const float* __restrict__ Wq,
                                              const float* __restrict__ bq,
                                              const float* __restrict__ Wk,
                                              const float* __restrict__ bk,
                                              float* __restrict__ ws) {
    int sel = blockIdx.y;
    int b = blockIdx.z;
    int n0 = blockIdx.x * NT;
    const float* src = sel ? audio : face;
    const float* W = sel ? Wk : Wq;
    const float* bias = sel ? bk : bq;
    float* dst = ws + (size_t)sel * BB * CQ * NN;

    __shared__ float flds[32][NT];
    int t = threadIdx.x;
    int n = t & 63;
    int wu = __builtin_amdgcn_readfirstlane(t >> 6);  // wave id 0..3

    float acc[16];
#pragma unroll
    for (int j = 0; j < 16; ++j) acc[j] = 0.f;

    for (int c0 = 0; c0 < CC; c0 += 32) {
        __syncthreads();
#pragma unroll
        for (int k = 0; k < 8; ++k) {
            int e = t + k * 256;
            flds[e >> 6][e & 63] =
                src[(size_t)b * CC * NN + (size_t)(c0 + (e >> 6)) * NN + n0 + (e & 63)];
        }
        __syncthreads();
        float f[32];
#pragma unroll
        for (int cc = 0; cc < 32; ++cc) f[cc] = flds[cc][n];
#pragma unroll
        for (int j = 0; j < 16; ++j) {
            const float* wr = W + (size_t)(wu * 16 + j) * CC + c0;
            float a = acc[j];
#pragma unroll
            for (int cc = 0; cc < 32; ++cc) a = fmaf(wr[cc], f[cc], a);
            acc[j] = a;
        }
    }
#pragma unroll
    for (int j = 0; j < 16; ++j) {
        int cq = wu * 16 + j;
        dst[(size_t)b * CQ * NN + (size_t)cq * NN + n0 + n] = acc[j] + bias[cq];
    }
}

// ---------------------------------------------------------------------------
// Fused: S = Q^T K / 8, P = exp(S) (unnormalized; |S| small so safe),
// Z[b][c][n] = (sum_m audio[b][c][m] * P[n][m]) / (sum_m P[n][m])  -> d_out
// grid (16 ntiles, B), block 512 (8 waves).
// Wave nb computes P rows {nb, nb+8, ...}; Z phase: thread owns 16 c-rows x 4 n-cols.
// ---------------------------------------------------------------------------
__global__ __launch_bounds__(512) void k_z(const float* __restrict__ Q,
                                           const float* __restrict__ Kw,
                                           const float* __restrict__ audio,
                                           float* __restrict__ Z) {
    int b = blockIdx.y;
    int n0 = blockIdx.x * NT;
    __shared__ float q_lds[CQ][NT];
    __shared__ float k_lds[CQ][NT];
    __shared__ float p_lds[NT][NT + 1];
    __shared__ float l_s[NT];
    int t = threadIdx.x;

#pragma unroll
    for (int k = 0; k < 8; ++k) {
        int e = t + k * 512;
        q_lds[e >> 6][e & 63] =
            Q[(size_t)b * CQ * NN + (size_t)(e >> 6) * NN + n0 + (e & 63)];
    }

    int m = t & 63;
    int nb = __builtin_amdgcn_readfirstlane(t >> 6);  // wave id 0..7
    int l16 = t & 15;
    int rowg = t >> 4;  // 0..31 -> c rows [16*rowg, 16*rowg+16)
    int nq0 = l16 * 4;  // 4 owned n columns
    const float* abase = audio + (size_t)b * CC * NN;

    float z[16][4];
#pragma unroll
    for (int r = 0; r < 16; ++r)
#pragma unroll
        for (int i = 0; i < 4; ++i) z[r][i] = 0.f;
    float lsum[8];
#pragma unroll
    for (int i = 0; i < 8; ++i) lsum[i] = 0.f;

#pragma unroll 1
    for (int mt = 0; mt < 16; ++mt) {
        int m0 = mt * NT;
        __syncthreads();  // protects p_lds (prev iter) + k_lds + initial q_lds
#pragma unroll
        for (int k = 0; k < 8; ++k) {
            int e = t + k * 512;
            k_lds[e >> 6][e & 63] =
                Kw[(size_t)b * CQ * NN + (size_t)(e >> 6) * NN + m0 + (e & 63)];
        }
        __syncthreads();
        // --- P tile: S[n][m] = sum_cq q[cq][n] k[cq][m]; p = exp(S/8)
        float s8[8];
#pragma unroll
        for (int i = 0; i < 8; ++i) s8[i] = 0.f;
        for (int cq = 0; cq < CQ; ++cq) {
            float kv = k_lds[cq][m];
#pragma unroll
            for (int i = 0; i < 8; ++i)
                s8[i] = fmaf(q_lds[cq][nb + 8 * i], kv, s8[i]);
        }
#pragma unroll
        for (int i = 0; i < 8; ++i) {
            float p = __expf(s8[i] * 0.125f);
            p_lds[nb + 8 * i][m] = p;
            lsum[i] += p;
        }
        __syncthreads();
        // --- Z accumulate: z[c][n] += audio[c][m] * P[n][m], m-chunks of 4
#pragma unroll 1
        for (int mc = 0; mc < 16; ++mc) {
            float pv[4][4];
#pragma unroll
            for (int k = 0; k < 4; ++k)
#pragma unroll
                for (int i = 0; i < 4; ++i)
                    pv[k][i] = p_lds[nq0 + i][mc * 4 + k];
#pragma unroll
            for (int r = 0; r < 16; ++r) {
                const float* ar =
                    abase + (size_t)(rowg * 16 + r) * NN + m0 + mc * 4;
                float4 a4 = *reinterpret_cast<const float4*>(ar);
                float av[4] = {a4.x, a4.y, a4.z, a4.w};
#pragma unroll
                for (int k = 0; k < 4; ++k)
#pragma unroll
                    for (int i = 0; i < 4; ++i)
                        z[r][i] = fmaf(av[k], pv[k][i], z[r][i]);
            }
        }
    }
    // reduce softmax denominators across the wave (lanes = m)
#pragma unroll
    for (int i = 0; i < 8; ++i) {
        float ssum = lsum[i];
#pragma unroll
        for (int off = 1; off < 64; off <<= 1) ssum += __shfl_xor(ssum, off, 64);
        if (m == 0) l_s[nb + 8 * i] = ssum;
    }
    __syncthreads();
    float linv[4];
#pragma unroll
    for (int i = 0; i < 4; ++i) linv[i] = 1.f / l_s[nq0 + i];
#pragma unroll
    for (int r = 0; r < 16; ++r) {
        float4 v = make_float4(z[r][0] * linv[0], z[r][1] * linv[1],
                               z[r][2] * linv[2], z[r][3] * linv[3]);
        *reinterpret_cast<float4*>(Z + (size_t)b * CC * NN +
                                   (size_t)(rowg * 16 + r) * NN + n0 + nq0) = v;
    }
}

// ---------------------------------------------------------------------------
// out[b][o][n] = gamma * (sum_c WvT[c][o] * Z[b][c][n] + bv[o]) + face[b][o][n]
// In place over d_out: stage Z column-tile to LDS first. grid (16, B), block 512.
// LDS tile [512][65] = 130 KB -> 1 block/CU (static LDS >64KB is fine on gfx950).
// ---------------------------------------------------------------------------
__global__ __launch_bounds__(512) void k_out(const float* __restrict__ WvT,
                                             const float* __restrict__ bv,
                                             const float* __restrict__ gamma,
                                             const float* __restrict__ face,
                                             float* __restrict__ Zio) {
    int b = blockIdx.y;
    int n0 = blockIdx.x * NT;
    __shared__ float z_lds[CC][NT + 1];
    int t = threadIdx.x;
#pragma unroll
    for (int k = 0; k < 64; ++k) {
        int e = t + k * 512;
        z_lds[e >> 6][e & 63] =
            Zio[(size_t)b * CC * NN + (size_t)(e >> 6) * NN + n0 + (e & 63)];
    }
    __syncthreads();
    int ol = t & 63;   // o lane
    int ng = t >> 6;   // 0..7, wave-uniform
    float acc[8][8];
#pragma unroll
    for (int k = 0; k < 8; ++k)
#pragma unroll
        for (int i = 0; i < 8; ++i) acc[k][i] = 0.f;
    for (int c = 0; c < CC; ++c) {
        float w8[8], z8[8];
#pragma unroll
        for (int k = 0; k < 8; ++k) w8[k] = WvT[(size_t)c * CC + ol + 64 * k];
#pragma unroll
        for (int i = 0; i < 8; ++i) z8[i] = z_lds[c][ng + 8 * i];
#pragma unroll
        for (int k = 0; k < 8; ++k)
#pragma unroll
            for (int i = 0; i < 8; ++i)
                acc[k][i] = fmaf(w8[k], z8[i], acc[k][i]);
    }
    __syncthreads();  // everyone done reading z_lds before overwrite
#pragma unroll
    for (int k = 0; k < 8; ++k)
#pragma unroll
        for (int i = 0; i < 8; ++i)
            z_lds[ol + 64 * k][ng + 8 * i] = acc[k][i];
    __syncthreads();
    float g = gamma[0];
#pragma unroll
    for (int k = 0; k < 64; ++k) {
        int e = t + k * 512;
        int o = e >> 6, nn = e & 63;
        size_t idx = (size_t)b * CC * NN + (size_t)o * NN + n0 + nn;
        Zio[idx] = g * (z_lds[o][nn] + bv[o]) + face[idx];
    }
}

// ---------------------------------------------------------------------------
extern "C" void kernel_launch(void* const* d_in, const int* in_sizes, int n_in,
                              void* d_out, int out_size, void* d_ws, size_t ws_size,
                              hipStream_t stream) {
    const float* face  = (const float*)d_in[0];
    const float* audio = (const float*)d_in[1];
    const float* Wq    = (const float*)d_in[2];
    const float* bq    = (const float*)d_in[3];
    const float* Wk    = (const float*)d_in[4];
    const float* bk    = (const float*)d_in[5];
    const float* Wv    = (const float*)d_in[6];
    const float* bv    = (const float*)d_in[7];
    const float* gamma = (const float*)d_in[8];
    float* out = (float*)d_out;
    float* ws  = (float*)d_ws;  // needs 2*8MB (Q,K) + 1MB (WvT) ~= 17 MB

    float* Qws = ws;
    float* Kws = ws + (size_t)BB * CQ * NN;
    float* WvT = ws + (size_t)2 * BB * CQ * NN;

    hipLaunchKernelGGL(k_transpose, dim3(16, 16), dim3(256), 0, stream, Wv, WvT);
    hipLaunchKernelGGL(k_proj, dim3(16, 2, BB), dim3(256), 0, stream,
                       face, audio, Wq, bq, Wk, bk, ws);
    hipLaunchKernelGGL(k_z, dim3(16, BB), dim3(512), 0, stream,
                       Qws, Kws, audio, out);
    hipLaunchKernelGGL(k_out, dim3(16, BB), dim3(512), 0, stream,
                       WvT, bv, gamma, face, out);
}

// Round 2
// 236.976 us; speedup vs baseline: 5.3165x; 5.3165x over previous
//
#include <hip/hip_runtime.h>
#include <math.h>

// Problem constants (fixed by reference)
#define BB 32     // batch
#define CC 512    // channels
#define CQ 64     // qk channels
#define NN 1024   // Nq = Nk = 32*32

typedef __attribute__((ext_vector_type(8))) short short8;   // 8 bf16 = 4 VGPR
typedef __attribute__((ext_vector_type(4))) float f32x4;    // MFMA C/D frag

#define MFMA16(a, b, c) __builtin_amdgcn_mfma_f32_16x16x32_bf16(a, b, c, 0, 0, 0)

__device__ __forceinline__ ushort f2bf(float f) {
    uint u = __builtin_bit_cast(uint, f);
    return (ushort)((u + 0x7FFFu + ((u >> 16) & 1u)) >> 16);  // RNE
}

// ---------------------------------------------------------------------------
// f32 -> bf16 bulk convert (n4 = n/4 vec4 elements), grid-stride
// ---------------------------------------------------------------------------
__global__ __launch_bounds__(256) void k_cvt(const float* __restrict__ in,
                                             ushort* __restrict__ out, int n4) {
    for (int i = blockIdx.x * 256 + threadIdx.x; i < n4; i += gridDim.x * 256) {
        float4 v = reinterpret_cast<const float4*>(in)[i];
        ushort4 o;
        o.x = f2bf(v.x); o.y = f2bf(v.y); o.z = f2bf(v.z); o.w = f2bf(v.w);
        reinterpret_cast<ushort4*>(out)[i] = o;
    }
}

// ---------------------------------------------------------------------------
// Qt[b][n][cq] = sum_c src[b][c][n]*W[cq][c] + bias[cq]   (bf16 out)
// MFMA: A = srcT[n][c] (LDS-transposed, f32->bf16 at read), B^T = W[cq][c].
// grid (16 ntiles, 2 sel, B), block 256 (4 waves). Wave w: n-rows [16w,16w+16).
// ---------------------------------------------------------------------------
__global__ __launch_bounds__(256) void k_proj(const float* __restrict__ face,
                                              const float* __restrict__ audio,
                                              const ushort* __restrict__ Wqb,
                                              const float* __restrict__ bq,
                                              const ushort* __restrict__ Wkb,
                                              const float* __restrict__ bk,
                                              ushort* __restrict__ Qt,
                                              ushort* __restrict__ Kt) {
    const int sel = blockIdx.y;
    const int b = blockIdx.z;
    const int n0 = blockIdx.x * 64;
    const float* src = sel ? audio : face;
    const ushort* Wb = sel ? Wkb : Wqb;
    const float* bias = sel ? bk : bq;
    ushort* dst = sel ? Kt : Qt;

    __shared__ float ldsT[64][33];  // [n][c-chunk], pad -> conflict-free
    const int t = threadIdx.x;
    const int w = __builtin_amdgcn_readfirstlane(t >> 6);  // wave 0..3
    const int l15 = t & 15;
    const int l4 = (t & 63) >> 4;

    f32x4 qacc[4];
#pragma unroll
    for (int j = 0; j < 4; ++j) qacc[j] = (f32x4){0.f, 0.f, 0.f, 0.f};

    for (int c0 = 0; c0 < CC; c0 += 32) {
        __syncthreads();
#pragma unroll
        for (int k = 0; k < 8; ++k) {
            int e = t + k * 256;
            int c = e >> 6, n = e & 63;
            ldsT[n][c] = src[((size_t)b * CC + c0 + c) * NN + n0 + n];
        }
        __syncthreads();
        // A fragment: row n = 16w + l15, k = c0 + 8*l4 + j  (convert f32->bf16)
        short8 af;
#pragma unroll
        for (int j = 0; j < 8; ++j)
            af[j] = (short)f2bf(ldsT[16 * w + l15][8 * l4 + j]);
#pragma unroll
        for (int cqj = 0; cqj < 4; ++cqj) {
            short8 wb = *reinterpret_cast<const short8*>(
                &Wb[(size_t)(16 * cqj + l15) * CC + c0 + 8 * l4]);
            qacc[cqj] = MFMA16(af, wb, qacc[cqj]);
        }
    }
#pragma unroll
    for (int cqj = 0; cqj < 4; ++cqj) {
        float bs = bias[16 * cqj + l15];
#pragma unroll
        for (int reg = 0; reg < 4; ++reg) {
            int n = n0 + 16 * w + 4 * l4 + reg;
            dst[((size_t)b * NN + n) * CQ + 16 * cqj + l15] =
                f2bf(qacc[cqj][reg] + bs);
        }
    }
}

// ---------------------------------------------------------------------------
// Fused S->P->Z:  S = Qt Kt^T / 8 ; P = exp(S) (unnormalized, |S| small);
// Zt[b][n][c] = (sum_m audio_b[c][m] * P[n][m]) / (sum_m P[n][m])   (bf16)
// grid (16 ntiles, B), block 512 (8 waves).
// S phase: wave w owns m-cols [16w,16w+16) of each 128-m strip.
// Z phase: wave w owns c-rows [64w,64w+64).
// ---------------------------------------------------------------------------
__global__ __launch_bounds__(512) void k_z(const ushort* __restrict__ Qt,
                                           const ushort* __restrict__ Kt,
                                           const ushort* __restrict__ audio_b,
                                           ushort* __restrict__ Zt) {
    const int b = blockIdx.y;
    const int n0 = blockIdx.x * 64;
    __shared__ ushort p_lds[64][136];  // bf16 P strip [n][m], pad 8 (+16B)
    __shared__ float l_part[8][64];
    __shared__ float linv_s[64];

    const int t = threadIdx.x;
    const int w = __builtin_amdgcn_readfirstlane(t >> 6);  // wave 0..7
    const int l15 = t & 15;
    const int l4 = (t & 63) >> 4;

    // Z accumulators: [ci 4][nj 4] frags of 16x16
    f32x4 zacc[4][4];
#pragma unroll
    for (int ci = 0; ci < 4; ++ci)
#pragma unroll
        for (int nj = 0; nj < 4; ++nj) zacc[ci][nj] = (f32x4){0.f, 0.f, 0.f, 0.f};
    float lacc[4][4];  // [ni][reg] partial row-sums of P (this wave's m-cols)
#pragma unroll
    for (int ni = 0; ni < 4; ++ni)
#pragma unroll
        for (int r = 0; r < 4; ++r) lacc[ni][r] = 0.f;

    // Q A-fragments (invariant): row n = n0 + 16ni + l15, k = cq = 32ks + 8l4
    short8 qa[4][2];
#pragma unroll
    for (int ni = 0; ni < 4; ++ni)
#pragma unroll
        for (int ks = 0; ks < 2; ++ks)
            qa[ni][ks] = *reinterpret_cast<const short8*>(
                &Qt[((size_t)b * NN + n0 + 16 * ni + l15) * CQ + 32 * ks + 8 * l4]);

    const ushort* abase = audio_b + (size_t)b * CC * NN;

#pragma unroll 1
    for (int mt = 0; mt < 8; ++mt) {
        const int m0 = mt * 128;
        // ---- S phase: this wave's 16 m-columns
        short8 kb[2];
#pragma unroll
        for (int ks = 0; ks < 2; ++ks)
            kb[ks] = *reinterpret_cast<const short8*>(
                &Kt[((size_t)b * NN + m0 + 16 * w + l15) * CQ + 32 * ks + 8 * l4]);
        f32x4 sacc[4];
#pragma unroll
        for (int ni = 0; ni < 4; ++ni) sacc[ni] = (f32x4){0.f, 0.f, 0.f, 0.f};
#pragma unroll
        for (int ni = 0; ni < 4; ++ni)
#pragma unroll
            for (int ks = 0; ks < 2; ++ks)
                sacc[ni] = MFMA16(qa[ni][ks], kb[ks], sacc[ni]);

        __syncthreads();  // previous Z phase done reading p_lds
#pragma unroll
        for (int ni = 0; ni < 4; ++ni)
#pragma unroll
            for (int reg = 0; reg < 4; ++reg) {
                float p = exp2f(sacc[ni][reg] * 0.1803368801111f);  // exp(S/8)
                lacc[ni][reg] += p;
                p_lds[16 * ni + 4 * l4 + reg][16 * w + l15] = f2bf(p);
            }
        __syncthreads();

        // ---- Z phase: this wave's 64 c-rows, K = 128 m in 4 steps
#pragma unroll
        for (int ks = 0; ks < 4; ++ks) {
            short8 af[4];
#pragma unroll
            for (int ci = 0; ci < 4; ++ci)
                af[ci] = *reinterpret_cast<const short8*>(
                    &abase[(size_t)(64 * w + 16 * ci + l15) * NN + m0 + 32 * ks + 8 * l4]);
            short8 pb[4];
#pragma unroll
            for (int nj = 0; nj < 4; ++nj)
                pb[nj] = *reinterpret_cast<const short8*>(
                    &p_lds[16 * nj + l15][32 * ks + 8 * l4]);
#pragma unroll
            for (int ci = 0; ci < 4; ++ci)
#pragma unroll
                for (int nj = 0; nj < 4; ++nj)
                    zacc[ci][nj] = MFMA16(af[ci], pb[nj], zacc[ci][nj]);
        }
    }

    // ---- softmax denominators: reduce lacc over the 16 lanes (m within wave)
#pragma unroll
    for (int ni = 0; ni < 4; ++ni)
#pragma unroll
        for (int reg = 0; reg < 4; ++reg) {
            float v = lacc[ni][reg];
            v += __shfl_xor(v, 1, 64);
            v += __shfl_xor(v, 2, 64);
            v += __shfl_xor(v, 4, 64);
            v += __shfl_xor(v, 8, 64);
            if (l15 == 0) l_part[w][16 * ni + 4 * l4 + reg] = v;
        }
    __syncthreads();
    if (t < 64) {
        float s = 0.f;
#pragma unroll
        for (int ww = 0; ww < 8; ++ww) s += l_part[ww][t];
        linv_s[t] = 1.f / s;
    }
    __syncthreads();

    // ---- write Zt[b][n][c], normalized, bf16 (4 consecutive c per store)
#pragma unroll
    for (int nj = 0; nj < 4; ++nj) {
        float linv = linv_s[16 * nj + l15];
#pragma unroll
        for (int ci = 0; ci < 4; ++ci) {
            ushort4 o;
            o.x = f2bf(zacc[ci][nj][0] * linv);
            o.y = f2bf(zacc[ci][nj][1] * linv);
            o.z = f2bf(zacc[ci][nj][2] * linv);
            o.w = f2bf(zacc[ci][nj][3] * linv);
            *reinterpret_cast<ushort4*>(
                &Zt[((size_t)b * NN + n0 + 16 * nj + l15) * CC + 64 * w + 16 * ci + 4 * l4]) = o;
        }
    }
}

// ---------------------------------------------------------------------------
// out[b][o][n] = gamma*(sum_c Wv[o][c]*Z[c][n] + bv[o]) + face[b][o][n]
// Pure MFMA GEMM, no LDS (Wvb 512KB L3-hot, Zt[b] 1MB L2-hot).
// grid (16 ntiles, B), block 512 (8 waves). Wave w: o-rows [64w,64w+64).
// ---------------------------------------------------------------------------
__global__ __launch_bounds__(512) void k_out(const ushort* __restrict__ Wvb,
                                             const ushort* __restrict__ Zt,
                                             const float* __restrict__ bv,
                                             const float* __restrict__ gamma,
                                             const float* __restrict__ face,
                                             float* __restrict__ out) {
    const int b = blockIdx.y;
    const int n0 = blockIdx.x * 64;
    const int t = threadIdx.x;
    const int w = __builtin_amdgcn_readfirstlane(t >> 6);
    const int l15 = t & 15;
    const int l4 = (t & 63) >> 4;

    f32x4 facc[4][4];
#pragma unroll
    for (int oi = 0; oi < 4; ++oi)
#pragma unroll
        for (int nj = 0; nj < 4; ++nj) facc[oi][nj] = (f32x4){0.f, 0.f, 0.f, 0.f};

#pragma unroll 1
    for (int ks = 0; ks < 16; ++ks) {
        short8 a[4];
#pragma unroll
        for (int oi = 0; oi < 4; ++oi)
            a[oi] = *reinterpret_cast<const short8*>(
                &Wvb[(size_t)(64 * w + 16 * oi + l15) * CC + 32 * ks + 8 * l4]);
        short8 zb[4];
#pragma unroll
        for (int nj = 0; nj < 4; ++nj)
            zb[nj] = *reinterpret_cast<const short8*>(
                &Zt[((size_t)b * NN + n0 + 16 * nj + l15) * CC + 32 * ks + 8 * l4]);
#pragma unroll
        for (int oi = 0; oi < 4; ++oi)
#pragma unroll
            for (int nj = 0; nj < 4; ++nj)
                facc[oi][nj] = MFMA16(a[oi], zb[nj], facc[oi][nj]);
    }

    const float g = gamma[0];
#pragma unroll
    for (int oi = 0; oi < 4; ++oi) {
#pragma unroll
        for (int reg = 0; reg < 4; ++reg) {
            int o = 64 * w + 16 * oi + 4 * l4 + reg;
            float bvo = bv[o];
#pragma unroll
            for (int nj = 0; nj < 4; ++nj) {
                int n = n0 + 16 * nj + l15;
                size_t idx = ((size_t)b * CC + o) * NN + n;
                out[idx] = g * (facc[oi][nj][reg] + bvo) + face[idx];
            }
        }
    }
}

// ---------------------------------------------------------------------------
extern "C" void kernel_launch(void* const* d_in, const int* in_sizes, int n_in,
                              void* d_out, int out_size, void* d_ws, size_t ws_size,
                              hipStream_t stream) {
    const float* face  = (const float*)d_in[0];
    const float* audio = (const float*)d_in[1];
    const float* Wq    = (const float*)d_in[2];
    const float* bq    = (const float*)d_in[3];
    const float* Wk    = (const float*)d_in[4];
    const float* bk    = (const float*)d_in[5];
    const float* Wv    = (const float*)d_in[6];
    const float* bv    = (const float*)d_in[7];
    const float* gamma = (const float*)d_in[8];
    float* out = (float*)d_out;
    char* ws = (char*)d_ws;

    // workspace layout (bytes)
    ushort* Qt      = (ushort*)(ws + 0);                       // 4 MB
    ushort* Kt      = (ushort*)(ws + (4u << 20));              // 4 MB
    ushort* audio_b = (ushort*)(ws + (8u << 20));              // 32 MB
    ushort* Zt      = (ushort*)(ws + (40u << 20));             // 32 MB
    ushort* Wqb     = (ushort*)(ws + (72u << 20));             // 64 KB
    ushort* Wkb     = (ushort*)(ws + (72u << 20) + (64u << 10));
    ushort* Wvb     = (ushort*)(ws + (72u << 20) + (128u << 10));  // 512 KB

    hipLaunchKernelGGL(k_cvt, dim3(32), dim3(256), 0, stream, Wq, Wqb, CQ * CC / 4);
    hipLaunchKernelGGL(k_cvt, dim3(32), dim3(256), 0, stream, Wk, Wkb, CQ * CC / 4);
    hipLaunchKernelGGL(k_cvt, dim3(256), dim3(256), 0, stream, Wv, Wvb, CC * CC / 4);
    hipLaunchKernelGGL(k_cvt, dim3(4096), dim3(256), 0, stream,
                       audio, audio_b, BB * CC * NN / 4);

    hipLaunchKernelGGL(k_proj, dim3(16, 2, BB), dim3(256), 0, stream,
                       face, audio, Wqb, bq, Wkb, bk, Qt, Kt);
    hipLaunchKernelGGL(k_z, dim3(16, BB), dim3(512), 0, stream,
                       Qt, Kt, audio_b, Zt);
    hipLaunchKernelGGL(k_out, dim3(16, BB), dim3(512), 0, stream,
                       Wvb, Zt, bv, gamma, face, out);
}

// Round 3
// 221.021 us; speedup vs baseline: 5.7003x; 1.0722x over previous
//
#include <hip/hip_runtime.h>
#include <math.h>

// Problem constants (fixed by reference)
#define BB 32     // batch
#define CC 512    // channels
#define CQ 64     // qk channels
#define NN 1024   // Nq = Nk = 32*32

typedef __attribute__((ext_vector_type(8))) short short8;   // 8 bf16 = 4 VGPR
typedef __attribute__((ext_vector_type(4))) float f32x4;    // MFMA C/D frag

#define MFMA16(a, b, c) __builtin_amdgcn_mfma_f32_16x16x32_bf16(a, b, c, 0, 0, 0)

// p_lds / z_lds row stride in ushorts: 512 + 8 pad -> 1040 B, 16B-aligned,
// ≡ 4 dwords mod 32 banks: the 16-row x 4-slot b128 read pattern spreads
// uniformly over all 32 banks (natural 8-cycle minimum, no extra conflict).
#define PSTR 520

__device__ __forceinline__ ushort f2bf(float f) {
    uint u = __builtin_bit_cast(uint, f);
    return (ushort)((u + 0x7FFFu + ((u >> 16) & 1u)) >> 16);  // RNE
}

// ---------------------------------------------------------------------------
// f32 -> bf16 bulk convert (n4 = n/4 vec4 elements), grid-stride (weights only)
// ---------------------------------------------------------------------------
__global__ __launch_bounds__(256) void k_cvt(const float* __restrict__ in,
                                             ushort* __restrict__ out, int n4) {
    for (int i = blockIdx.x * 256 + threadIdx.x; i < n4; i += gridDim.x * 256) {
        float4 v = reinterpret_cast<const float4*>(in)[i];
        ushort4 o;
        o.x = f2bf(v.x); o.y = f2bf(v.y); o.z = f2bf(v.z); o.w = f2bf(v.w);
        reinterpret_cast<ushort4*>(out)[i] = o;
    }
}

// ---------------------------------------------------------------------------
// Qt[b][n][cq] = sum_c src[b][c][n]*W[cq][c] + bias[cq]   (bf16 out)
// sel=1 additionally emits audio_b (bf16 copy of audio) from the staged loads.
// grid (16 ntiles, 2 sel, B), block 256 (4 waves).
// ---------------------------------------------------------------------------
__global__ __launch_bounds__(256) void k_proj(const float* __restrict__ face,
                                              const float* __restrict__ audio,
                                              const ushort* __restrict__ Wqb,
                                              const float* __restrict__ bq,
                                              const ushort* __restrict__ Wkb,
                                              const float* __restrict__ bk,
                                              ushort* __restrict__ Qt,
                                              ushort* __restrict__ Kt,
                                              ushort* __restrict__ audio_b) {
    const int sel = blockIdx.y;
    const int b = blockIdx.z;
    const int n0 = blockIdx.x * 64;
    const float* src = sel ? audio : face;
    const ushort* Wb = sel ? Wkb : Wqb;
    const float* bias = sel ? bk : bq;
    ushort* dst = sel ? Kt : Qt;

    __shared__ float ldsT[64][33];  // [n][c-chunk]
    const int t = threadIdx.x;
    const int w = __builtin_amdgcn_readfirstlane(t >> 6);  // wave 0..3
    const int l15 = t & 15;
    const int l4 = (t & 63) >> 4;

    f32x4 qacc[4];
#pragma unroll
    for (int j = 0; j < 4; ++j) qacc[j] = (f32x4){0.f, 0.f, 0.f, 0.f};

    for (int c0 = 0; c0 < CC; c0 += 32) {
        __syncthreads();
#pragma unroll
        for (int k = 0; k < 8; ++k) {
            int e = t + k * 256;
            int c = e >> 6, n = e & 63;
            float v = src[((size_t)b * CC + c0 + c) * NN + n0 + n];
            ldsT[n][c] = v;
            if (sel)
                audio_b[((size_t)b * CC + c0 + c) * NN + n0 + n] = f2bf(v);
        }
        __syncthreads();
        short8 af;
#pragma unroll
        for (int j = 0; j < 8; ++j)
            af[j] = (short)f2bf(ldsT[16 * w + l15][8 * l4 + j]);
#pragma unroll
        for (int cqj = 0; cqj < 4; ++cqj) {
            short8 wb = *reinterpret_cast<const short8*>(
                &Wb[(size_t)(16 * cqj + l15) * CC + c0 + 8 * l4]);
            qacc[cqj] = MFMA16(af, wb, qacc[cqj]);
        }
    }
#pragma unroll
    for (int cqj = 0; cqj < 4; ++cqj) {
        float bs = bias[16 * cqj + l15];
#pragma unroll
        for (int reg = 0; reg < 4; ++reg) {
            int n = n0 + 16 * w + 4 * l4 + reg;
            dst[((size_t)b * NN + n) * CQ + 16 * cqj + l15] =
                f2bf(qacc[cqj][reg] + bs);
        }
    }
}

// ---------------------------------------------------------------------------
// Fused attention + output GEMM, one block per (b, 128-n-tile). grid 256,
// block 512 (8 waves), 1 block/CU.
//   S:  P[n][m] = exp(Qt Kt^T / 8) for an m-strip of 512 (2 strips)
//   Z:  zacc[c][n] += audio[c][m] * P[n][m]   (wave = 64 c-rows)
//   l:  row-sums of P accumulated into LDS
//   O:  out = gamma*(Wv . Znorm + bv) + face  (Znorm staged in LDS [n][c])
// ---------------------------------------------------------------------------
__global__ __launch_bounds__(512, 2) void k_attn(
    const ushort* __restrict__ Qt, const ushort* __restrict__ Kt,
    const ushort* __restrict__ Ab_, const ushort* __restrict__ Wvb,
    const float* __restrict__ bv, const float* __restrict__ gamma,
    const float* __restrict__ face, float* __restrict__ out) {
    __shared__ ushort smem[128 * PSTR];   // P strip [128n][512m] / Z [128n][512c]
    __shared__ float l_part[8][128];
    __shared__ float linv[128];

    // XCD-chunked swizzle: the 8 n-tiles of one b land on one XCD's L2.
    const int wg = blockIdx.x;
    const int swz = (wg & 7) * 32 + (wg >> 3);
    const int b = swz >> 3;
    const int n0 = (swz & 7) * 128;

    const int t = threadIdx.x;
    const int w = __builtin_amdgcn_readfirstlane(t >> 6);  // wave 0..7
    const int l15 = t & 15;
    const int l4 = (t & 63) >> 4;

    const ushort* Qb = Qt + ((size_t)b * NN + n0) * CQ;
    const ushort* Kb = Kt + (size_t)b * NN * CQ;
    const ushort* Ab = Ab_ + (size_t)b * CC * NN;

    f32x4 zacc[4][8];  // [ci][nj]: c = 64w+16ci, n = 16nj
#pragma unroll
    for (int ci = 0; ci < 4; ++ci)
#pragma unroll
        for (int nj = 0; nj < 8; ++nj) zacc[ci][nj] = (f32x4){0.f, 0.f, 0.f, 0.f};

#pragma unroll 1
    for (int s = 0; s < 2; ++s) {
        const int m0 = s * 512;
        __syncthreads();  // strip s-1 Z-phase done reading smem
        // ---- S phase: wave w owns m-cols [m0+64w, +64)
        short8 kb[4][2];
#pragma unroll
        for (int mj = 0; mj < 4; ++mj)
#pragma unroll
            for (int ks = 0; ks < 2; ++ks)
                kb[mj][ks] = *reinterpret_cast<const short8*>(
                    &Kb[(size_t)(m0 + 64 * w + 16 * mj + l15) * CQ + 32 * ks + 8 * l4]);
#pragma unroll
        for (int nip = 0; nip < 4; ++nip) {
            short8 qa[2][2];
#pragma unroll
            for (int i = 0; i < 2; ++i)
#pragma unroll
                for (int ks = 0; ks < 2; ++ks)
                    qa[i][ks] = *reinterpret_cast<const short8*>(
                        &Qb[(size_t)(32 * nip + 16 * i + l15) * CQ + 32 * ks + 8 * l4]);
            f32x4 sacc[2][4];
#pragma unroll
            for (int i = 0; i < 2; ++i)
#pragma unroll
                for (int mj = 0; mj < 4; ++mj) {
                    sacc[i][mj] = (f32x4){0.f, 0.f, 0.f, 0.f};
                    sacc[i][mj] = MFMA16(qa[i][0], kb[mj][0], sacc[i][mj]);
                    sacc[i][mj] = MFMA16(qa[i][1], kb[mj][1], sacc[i][mj]);
                }
#pragma unroll
            for (int i = 0; i < 2; ++i) {
                const int prow = 32 * nip + 16 * i + 4 * l4;
                float ls[4] = {0.f, 0.f, 0.f, 0.f};
#pragma unroll
                for (int mj = 0; mj < 4; ++mj)
#pragma unroll
                    for (int reg = 0; reg < 4; ++reg) {
                        float p = exp2f(sacc[i][mj][reg] * 0.18033688011112f);
                        ls[reg] += p;
                        smem[(prow + reg) * PSTR + 64 * w + 16 * mj + l15] = f2bf(p);
                    }
#pragma unroll
                for (int reg = 0; reg < 4; ++reg) {
                    float v = ls[reg];
                    v += __shfl_xor(v, 1, 64);
                    v += __shfl_xor(v, 2, 64);
                    v += __shfl_xor(v, 4, 64);
                    v += __shfl_xor(v, 8, 64);
                    if (l15 == 0) {
                        int n = prow + reg;
                        l_part[w][n] = s ? (l_part[w][n] + v) : v;
                    }
                }
            }
        }
        __syncthreads();
        // ---- Z phase: wave w owns c-rows [64w, +64), K = 512 m
#pragma unroll 4
        for (int ks = 0; ks < 16; ++ks) {
            short8 af[4];
#pragma unroll
            for (int ci = 0; ci < 4; ++ci)
                af[ci] = *reinterpret_cast<const short8*>(
                    &Ab[(size_t)(64 * w + 16 * ci + l15) * NN + m0 + 32 * ks + 8 * l4]);
            short8 pb[8];
#pragma unroll
            for (int nj = 0; nj < 8; ++nj)
                pb[nj] = *reinterpret_cast<const short8*>(
                    &smem[(16 * nj + l15) * PSTR + 32 * ks + 8 * l4]);
#pragma unroll
            for (int ci = 0; ci < 4; ++ci)
#pragma unroll
                for (int nj = 0; nj < 8; ++nj)
                    zacc[ci][nj] = MFMA16(af[ci], pb[nj], zacc[ci][nj]);
        }
    }

    __syncthreads();
    if (t < 128) {
        float ssum = 0.f;
#pragma unroll
        for (int ww = 0; ww < 8; ++ww) ssum += l_part[ww][t];
        linv[t] = 1.f / ssum;
    }
    __syncthreads();

    // ---- normalize + stage Z to LDS as [n][c]
    float li[8];
#pragma unroll
    for (int nj = 0; nj < 8; ++nj) li[nj] = linv[16 * nj + l15];
#pragma unroll
    for (int ci = 0; ci < 4; ++ci)
#pragma unroll
        for (int nj = 0; nj < 8; ++nj) {
            ushort4 o4;
            o4.x = f2bf(zacc[ci][nj][0] * li[nj]);
            o4.y = f2bf(zacc[ci][nj][1] * li[nj]);
            o4.z = f2bf(zacc[ci][nj][2] * li[nj]);
            o4.w = f2bf(zacc[ci][nj][3] * li[nj]);
            *reinterpret_cast<ushort4*>(
                &smem[(16 * nj + l15) * PSTR + 64 * w + 16 * ci + 4 * l4]) = o4;
        }
    __syncthreads();

    // ---- O phase: out-rows o = [64w, +64), K = 512 c
    f32x4 facc[4][8];
#pragma unroll
    for (int oi = 0; oi < 4; ++oi)
#pragma unroll
        for (int nj = 0; nj < 8; ++nj) facc[oi][nj] = (f32x4){0.f, 0.f, 0.f, 0.f};
#pragma unroll 4
    for (int ks = 0; ks < 16; ++ks) {
        short8 wa[4];
#pragma unroll
        for (int oi = 0; oi < 4; ++oi)
            wa[oi] = *reinterpret_cast<const short8*>(
                &Wvb[(size_t)(64 * w + 16 * oi + l15) * CC + 32 * ks + 8 * l4]);
        short8 zb[8];
#pragma unroll
        for (int nj = 0; nj < 8; ++nj)
            zb[nj] = *reinterpret_cast<const short8*>(
                &smem[(16 * nj + l15) * PSTR + 32 * ks + 8 * l4]);
#pragma unroll
        for (int oi = 0; oi < 4; ++oi)
#pragma unroll
            for (int nj = 0; nj < 8; ++nj)
                facc[oi][nj] = MFMA16(wa[oi], zb[nj], facc[oi][nj]);
    }

    // ---- epilogue
    const float g = gamma[0];
#pragma unroll
    for (int oi = 0; oi < 4; ++oi)
#pragma unroll
        for (int reg = 0; reg < 4; ++reg) {
            int o = 64 * w + 16 * oi + 4 * l4 + reg;
            float bvo = bv[o];
#pragma unroll
            for (int nj = 0; nj < 8; ++nj) {
                int n = n0 + 16 * nj + l15;
                size_t idx = ((size_t)b * CC + o) * NN + n;
                out[idx] = g * (facc[oi][nj][reg] + bvo) + face[idx];
            }
        }
}

// ---------------------------------------------------------------------------
extern "C" void kernel_launch(void* const* d_in, const int* in_sizes, int n_in,
                              void* d_out, int out_size, void* d_ws, size_t ws_size,
                              hipStream_t stream) {
    const float* face  = (const float*)d_in[0];
    const float* audio = (const float*)d_in[1];
    const float* Wq    = (const float*)d_in[2];
    const float* bq    = (const float*)d_in[3];
    const float* Wk    = (const float*)d_in[4];
    const float* bk    = (const float*)d_in[5];
    const float* Wv    = (const float*)d_in[6];
    const float* bv    = (const float*)d_in[7];
    const float* gamma = (const float*)d_in[8];
    float* out = (float*)d_out;
    char* ws = (char*)d_ws;

    // workspace layout (bytes)
    ushort* Qt      = (ushort*)(ws + 0);                       // 4 MB
    ushort* Kt      = (ushort*)(ws + (4u << 20));              // 4 MB
    ushort* audio_b = (ushort*)(ws + (8u << 20));              // 32 MB
    ushort* Wqb     = (ushort*)(ws + (40u << 20));             // 64 KB
    ushort* Wkb     = (ushort*)(ws + (40u << 20) + (64u << 10));
    ushort* Wvb     = (ushort*)(ws + (40u << 20) + (128u << 10));  // 512 KB

    hipLaunchKernelGGL(k_cvt, dim3(32), dim3(256), 0, stream, Wq, Wqb, CQ * CC / 4);
    hipLaunchKernelGGL(k_cvt, dim3(32), dim3(256), 0, stream, Wk, Wkb, CQ * CC / 4);
    hipLaunchKernelGGL(k_cvt, dim3(256), dim3(256), 0, stream, Wv, Wvb, CC * CC / 4);

    hipLaunchKernelGGL(k_proj, dim3(16, 2, BB), dim3(256), 0, stream,
                       face, audio, Wqb, bq, Wkb, bk, Qt, Kt, audio_b);
    hipLaunchKernelGGL(k_attn, dim3(256), dim3(512), 0, stream,
                       Qt, Kt, audio_b, Wvb, bv, gamma, face, out);
}